// Round 14
// baseline (4606.298 us; speedup 1.0000x reference)
//
#include <hip/hip_runtime.h>
#include <math.h>

#define BB 16384
#define BM 128
#define BN 128
#define BK 32

typedef float f32x2 __attribute__((ext_vector_type(2)));

// ---------------------------------------------------------------------------
// ctx = concat(input[B,510], task[B,514]) -> [B,1024] fp32 (exact)
// ---------------------------------------------------------------------------
__global__ __launch_bounds__(256) void concat_kernel(const float* __restrict__ inp,
    const float* __restrict__ task, float* __restrict__ ctx)
{
  int idx = blockIdx.x * 256 + threadIdx.x;
  int b = idx >> 10;
  int c = idx & 1023;
  float v;
  if (c < 510) v = inp[(size_t)b * 510 + c];
  else         v = task[(size_t)b * 514 + (c - 510)];
  ctx[idx] = v;
}

// ---------------------------------------------------------------------------
// Bitwise-BLAS fp32 GEMM, K-chunking = FIXED 384-blocks, remainder last:
// K=1024 -> [384,384,256] (fold after BK-tiles 11,23,31), K=512 -> [384,128]
// (fold after 11,15). Per kc-block: single ascending-k fp32 FMA chain per C
// element; blocks folded left-assoc (C += partial). Verified np match (r7)
// -- DO NOT REORDER chains or fold points.
// r14 change: 512 threads, 4x8 micro (res+cur = 64 floats/thread, ~half the
// register footprint) -> no AGPR parking of hot accumulators (r13 diag:
// ~650k/SIMD mystery VALU cycles ~= v_accvgpr_read/write wrapped FMAs), and
// 4 waves/SIMD TLP (was 2) at the same 128x128 tile. Dbuf single barrier,
// packed v_pk_fma_f32 (per-component IEEE fp32 == fmaf), LDS XOR swizzle
// [k][r^(k&28)] (0 conflicts), bijective XCD chunk swizzle.
// post (CIN=0): acc + b1 ; post (CIN=1): ((Cin + b1) + acc) + b2 (np order)
// tanh: correctly-rounded via double.
// ---------------------------------------------------------------------------
template<bool TANH, bool CIN>
__global__ __launch_bounds__(512, 2) void gemm32g_kernel(
    const float* __restrict__ A, const float* __restrict__ W,
    const float* __restrict__ b1, const float* __restrict__ b2,
    const float* __restrict__ Cin, float* __restrict__ C,
    int N, int K, int lda, int ldw, unsigned foldmask)
{
  __shared__ float As[2][BK * BM];
  __shared__ float Bs[2][BK * BN];
  const int tid = threadIdx.x;
  const int tx = tid & 31;            // 4 cols: 4*tx .. 4*tx+3 (covers 128)
  const int ty = tid >> 5;            // 8 rows: 4*ty.. and 64+4*ty.. (0..15)
  // XCD-chunked bijective block swizzle (nwg multiple of 8 by construction)
  const int gx = gridDim.x;
  const int nwg = gx * gridDim.y;
  const int flat = blockIdx.y * gx + blockIdx.x;
  const int cpx = nwg >> 3;
  const int swb = (flat & 7) * cpx + (flat >> 3);
  const int m0 = (swb / gx) * BM;
  const int n0 = (swb % gx) * BN;
  const int srow = tid >> 3;          // 0..63 (staging rows srow, srow+64)
  const int kc = (tid & 7) << 2;      // 0,4,...,28

  f32x2 res[2][4][2], cur[2][4][2];
#pragma unroll
  for (int g = 0; g < 2; ++g)
#pragma unroll
    for (int i = 0; i < 4; ++i)
#pragma unroll
      for (int jp = 0; jp < 2; ++jp) {
        res[g][i][jp] = (f32x2){0.f, 0.f};
        cur[g][i][jp] = (f32x2){0.f, 0.f};
      }

  float4 ra[2], rb[2];
  const int NT = K / BK;

  auto loadG = [&](int kt) {
    int kb = kt * BK;
#pragma unroll
    for (int i = 0; i < 2; ++i) {
      int r = srow + (i << 6);
      ra[i] = *(const float4*)(A + (size_t)(m0 + r) * lda + kb + kc);
      rb[i] = *(const float4*)(W + (size_t)(n0 + r) * ldw + kb + kc);
    }
  };
  auto stage = [&](int p) {
#pragma unroll
    for (int i = 0; i < 2; ++i) {
      int cS = (srow + (i << 6)) ^ kc;      // 2-way max write aliasing (free)
      As[p][(kc + 0) * BM + cS] = ra[i].x;
      As[p][(kc + 1) * BM + cS] = ra[i].y;
      As[p][(kc + 2) * BM + cS] = ra[i].z;
      As[p][(kc + 3) * BM + cS] = ra[i].w;
      Bs[p][(kc + 0) * BN + cS] = rb[i].x;
      Bs[p][(kc + 1) * BN + cS] = rb[i].y;
      Bs[p][(kc + 2) * BN + cS] = rb[i].z;
      Bs[p][(kc + 3) * BN + cS] = rb[i].w;
    }
  };

  // prologue: stage kt=0 into buf0; start loads for kt=1
  loadG(0);
  stage(0);
  __syncthreads();
  if (NT > 1) loadG(1);

  for (int kt = 0; kt < NT; ++kt) {
    const int p = kt & 1;
    if (kt + 1 < NT) {
      stage(p ^ 1);
      if (kt + 2 < NT) loadG(kt + 2);
    }
    // compute from buf[p]: fully-unrolled kk, 2-deep fragment pipeline
    {
      const float* Ap = As[p];
      const float* Bp = Bs[p];
      float4 a0f[2], a1f[2], b0f[2];
      a0f[0] = *(const float4*)&Ap[(4 * ty)];
      a1f[0] = *(const float4*)&Ap[64 + (4 * ty)];
      b0f[0] = *(const float4*)&Bp[(4 * tx)];
#pragma unroll
      for (int kk = 0; kk < BK; ++kk) {
        const int q = kk & 1;
        if (kk + 1 < BK) {
          const int swz = (kk + 1) & 28;
          a0f[q ^ 1] = *(const float4*)&Ap[(kk + 1) * BM + ((4 * ty) ^ swz)];
          a1f[q ^ 1] = *(const float4*)&Ap[(kk + 1) * BM + 64 + ((4 * ty) ^ swz)];
          b0f[q ^ 1] = *(const float4*)&Bp[(kk + 1) * BN + ((4 * tx) ^ swz)];
        }
        const float av[2][4] = {{a0f[q].x, a0f[q].y, a0f[q].z, a0f[q].w},
                                {a1f[q].x, a1f[q].y, a1f[q].z, a1f[q].w}};
        const f32x2 wv2[2] = {(f32x2){b0f[q].x, b0f[q].y},
                              (f32x2){b0f[q].z, b0f[q].w}};
#pragma unroll
        for (int g = 0; g < 2; ++g)
#pragma unroll
          for (int i = 0; i < 4; ++i) {
            const f32x2 as = (f32x2){av[g][i], av[g][i]};
#pragma unroll
            for (int jp = 0; jp < 2; ++jp)
              cur[g][i][jp] =
                  __builtin_elementwise_fma(as, wv2[jp], cur[g][i][jp]);
          }
      }
    }
    if ((foldmask >> kt) & 1u) {        // kc-block boundary: C += partial
#pragma unroll
      for (int g = 0; g < 2; ++g)
#pragma unroll
        for (int i = 0; i < 4; ++i)
#pragma unroll
          for (int jp = 0; jp < 2; ++jp) {
            res[g][i][jp] = res[g][i][jp] + cur[g][i][jp];  // v_pk_add_f32
            cur[g][i][jp] = (f32x2){0.f, 0.f};
          }
    }
    __syncthreads();                    // single barrier per kt
  }

  // epilogue with np-exact rounding order
  float4 b1v, b2v;
  {
    int cb = n0 + 4 * tx;
    b1v = b1 ? *(const float4*)&b1[cb] : make_float4(0.f, 0.f, 0.f, 0.f);
    b2v = (CIN && b2) ? *(const float4*)&b2[cb] : make_float4(0.f, 0.f, 0.f, 0.f);
  }
#pragma unroll
  for (int g = 0; g < 2; ++g)
#pragma unroll
    for (int i = 0; i < 4; ++i) {
      int row = m0 + g * 64 + 4 * ty + i;
      int col = n0 + 4 * tx;
      const float rs[4] = {res[g][i][0][0], res[g][i][0][1],
                           res[g][i][1][0], res[g][i][1][1]};
      float4 o;
      if (CIN) {
        float4 ci = *(const float4*)&Cin[(size_t)row * N + col];
        o.x = ((ci.x + b1v.x) + rs[0]) + b2v.x;
        o.y = ((ci.y + b1v.y) + rs[1]) + b2v.y;
        o.z = ((ci.z + b1v.z) + rs[2]) + b2v.z;
        o.w = ((ci.w + b1v.w) + rs[3]) + b2v.w;
      } else if (b1) {
        o.x = rs[0] + b1v.x;
        o.y = rs[1] + b1v.y;
        o.z = rs[2] + b1v.z;
        o.w = rs[3] + b1v.w;
      } else {
        o.x = rs[0]; o.y = rs[1]; o.z = rs[2]; o.w = rs[3];
      }
      if (TANH) {
        o.x = (float)tanh((double)o.x);
        o.y = (float)tanh((double)o.y);
        o.z = (float)tanh((double)o.z);
        o.w = (float)tanh((double)o.w);
      }
      *(float4*)&C[(size_t)row * N + col] = o;
    }
}

// ---------------------------------------------------------------------------
// kwta replicating np-fp32 (verified round 7): cxz = softmax LOGITS row.
//   m = max(z); e = expCR(z-m); s = numpy-pairwise-sum(e); u = e/s
//   k = first-argmax(u); thr = ascending-rank-(N-k) of x (exact radix select)
//   out = (k>0 && x>=thr) ? x : x/3.0f   (in-place safe)
// ---------------------------------------------------------------------------
template<int NELEM>
__global__ __launch_bounds__(256) void kwta_kernel(const float* __restrict__ x,
    const float* __restrict__ cxz, float* __restrict__ out)
{
  constexpr int NPER = NELEM / 256;
  const int row = blockIdx.x;
  const int tid = threadIdx.x;
  const float* xr = x + (size_t)row * NELEM;
  const float* zr = cxz + (size_t)row * NELEM;
  float* orow = out + (size_t)row * NELEM;

  __shared__ float es[NELEM];
  __shared__ float red[256];
  __shared__ int   ri[256];
  __shared__ float bs[8];
  __shared__ float ssum;
  __shared__ unsigned hist[256];
  __shared__ unsigned cum[256];
  __shared__ int selBin;
  __shared__ unsigned selBase;

  float zv[NPER];
  float mx = -INFINITY;
#pragma unroll
  for (int j = 0; j < NPER; ++j) {
    zv[j] = zr[tid + (j << 8)];
    mx = fmaxf(mx, zv[j]);
  }
  red[tid] = mx;
  __syncthreads();
  for (int s = 128; s > 0; s >>= 1) {
    if (tid < s) red[tid] = fmaxf(red[tid], red[tid + s]);
    __syncthreads();
  }
  mx = red[0];
  __syncthreads();

  float ev[NPER];
#pragma unroll
  for (int j = 0; j < NPER; ++j) {
    float d = zv[j] - mx;
    ev[j] = (float)exp((double)d);              // correctly-rounded expf
    es[tid + (j << 8)] = ev[j];
  }
  __syncthreads();

  if (tid < NELEM / 128) {                      // numpy pairwise 128-blocks
    const float* a = &es[tid * 128];
    float r0 = a[0], r1 = a[1], r2 = a[2], r3 = a[3];
    float r4 = a[4], r5 = a[5], r6 = a[6], r7 = a[7];
    for (int i = 8; i < 128; i += 8) {
      r0 += a[i + 0]; r1 += a[i + 1]; r2 += a[i + 2]; r3 += a[i + 3];
      r4 += a[i + 4]; r5 += a[i + 5]; r6 += a[i + 6]; r7 += a[i + 7];
    }
    bs[tid] = ((r0 + r1) + (r2 + r3)) + ((r4 + r5) + (r6 + r7));
  }
  __syncthreads();
  if (tid == 0) {
    float s;
    if (NELEM == 1024)
      s = ((bs[0] + bs[1]) + (bs[2] + bs[3])) + ((bs[4] + bs[5]) + (bs[6] + bs[7]));
    else
      s = (bs[0] + bs[1]) + (bs[2] + bs[3]);
    ssum = s;
  }
  __syncthreads();
  const float s = ssum;

  float bv = -INFINITY; int bi = 0x7fffffff;
#pragma unroll
  for (int j = 0; j < NPER; ++j) {
    float u = ev[j] / s;
    int i = tid + (j << 8);
    if (u > bv) { bv = u; bi = i; }
  }
  red[tid] = bv; ri[tid] = bi;
  __syncthreads();
  for (int st = 128; st > 0; st >>= 1) {
    if (tid < st) {
      float ov = red[tid + st]; int oi = ri[tid + st];
      if (ov > red[tid] || (ov == red[tid] && oi < ri[tid])) { red[tid] = ov; ri[tid] = oi; }
    }
    __syncthreads();
  }
  const int k = ri[0];

  float xv[NPER]; unsigned key[NPER];
#pragma unroll
  for (int j = 0; j < NPER; ++j) {
    float v = xr[tid + (j << 8)];
    xv[j] = v;
    unsigned sb = __float_as_uint(v);
    key[j] = (sb & 0x80000000u) ? ~sb : (sb | 0x80000000u);
  }

  float thr = 0.f;
  const bool kzero = (k == 0);
  if (!kzero) {
    unsigned ur = (unsigned)(NELEM - k);        // ascending 0-indexed rank
    unsigned prefix = 0, pmask = 0;
    for (int shift = 24; shift >= 0; shift -= 8) {
      hist[tid] = 0;
      __syncthreads();
#pragma unroll
      for (int j = 0; j < NPER; ++j)
        if ((key[j] & pmask) == prefix) atomicAdd(&hist[(key[j] >> shift) & 255u], 1u);
      __syncthreads();
      unsigned v = hist[tid];
      cum[tid] = v;
      __syncthreads();
      for (int d = 1; d < 256; d <<= 1) {
        unsigned t = (tid >= d) ? cum[tid - d] : 0u;
        __syncthreads();
        v += t; cum[tid] = v;
        __syncthreads();
      }
      unsigned excl = v - hist[tid];
      if (ur >= excl && ur < v) { selBin = tid; selBase = excl; }
      __syncthreads();
      prefix |= ((unsigned)selBin) << shift;
      pmask  |= (255u << shift);
      ur -= selBase;
      __syncthreads();
    }
    thr = (prefix & 0x80000000u) ? __uint_as_float(prefix & 0x7FFFFFFFu)
                                 : __uint_as_float(~prefix);
  }
#pragma unroll
  for (int j = 0; j < NPER; ++j) {
    float v = xv[j];
    bool keep = !kzero && (v >= thr);
    orow[tid + (j << 8)] = keep ? v : (v / 3.0f);
  }
}

// ---------------------------------------------------------------------------
// Schedule: fp32, 2 ws slots (R*1024 fp32 each), row-chunked (fits ws_size).
//   concat -> out_x.  Per chunk:
//   p1 M1=ctx@w_ihT -> S0;  p2 out=tanh(((M1+b_ih)+h0@w_hhT)+b_hh) -> out_h
//   t1->S1; cx1->S0; x1->OX; kw1(OX,S0)->OX;
//   t2->S1.lo; cx2->S1.hi; x2->S0.lo; kw2(S0.lo,S1.hi)->S0.lo;
//   t3->S1; cx3->OX; x3->S1; kw3(S1,OX)->S1; x4->OX (final).
// ---------------------------------------------------------------------------
extern "C" void kernel_launch(void* const* d_in, const int* in_sizes, int n_in,
                              void* d_out, int out_size, void* d_ws, size_t ws_size,
                              hipStream_t stream) {
  const float* input  = (const float*)d_in[0];
  const float* task   = (const float*)d_in[1];
  const float* hidden = (const float*)d_in[2];
  const float* w_ih   = (const float*)d_in[3];  const float* b_ih   = (const float*)d_in[4];
  const float* w_hh   = (const float*)d_in[5];  const float* b_hh   = (const float*)d_in[6];
  const float* w_cx11 = (const float*)d_in[7];  const float* b_cx11 = (const float*)d_in[8];
  const float* w_cx12 = (const float*)d_in[9];  const float* b_cx12 = (const float*)d_in[10];
  const float* w_cx21 = (const float*)d_in[11]; const float* b_cx21 = (const float*)d_in[12];
  const float* w_cx22 = (const float*)d_in[13]; const float* b_cx22 = (const float*)d_in[14];
  const float* w_cx31 = (const float*)d_in[15]; const float* b_cx31 = (const float*)d_in[16];
  const float* w_cx32 = (const float*)d_in[17]; const float* b_cx32 = (const float*)d_in[18];
  const float* w_l1   = (const float*)d_in[19]; const float* b_l1   = (const float*)d_in[20];
  const float* w_l2   = (const float*)d_in[21]; const float* b_l2   = (const float*)d_in[22];
  const float* w_l3   = (const float*)d_in[23]; const float* b_l3   = (const float*)d_in[24];
  const float* w_l4   = (const float*)d_in[25]; const float* b_l4   = (const float*)d_in[26];

  float* out_x = (float*)d_out;                 // x [B,1024]; ctx scratch until final
  float* out_h = out_x + (size_t)BB * 1024;     // next_hidden [B,1024]

  int R = BB;                                   // 2 slots * R*4096 B <= ws_size
  while ((size_t)R * 8192 > ws_size && R > 128) R >>= 1;
  const int nChunks = BB / R;

  // Fixed-384 K-chunking (verified round 7): K=1024 -> [384,384,256]
  // (folds after BK-tiles 11,23,31); K=512 -> [384,128] (folds after 11,15).
  const unsigned FM1024 = (1u << 11) | (1u << 23) | (1u << 31);
  const unsigned FM512  = (1u << 11) | (1u << 15);

  dim3 blk(256);
  dim3 gblk(512);

  concat_kernel<<<BB * 1024 / 256, blk, 0, stream>>>(input, task, out_x);

  for (int c = 0; c < nChunks; ++c) {
    const size_t r0 = (size_t)c * R;
    float* S0 = (float*)d_ws;
    float* S1 = S0 + (size_t)R * 1024;
    float* S1hi = S1 + (size_t)R * 512;
    float* OX = out_x + r0 * 1024;
    const float* ctx_c = OX;
    const float* hid_c = hidden + r0 * 1024;
    float* out_c = out_h + r0 * 1024;
    // grid: x = n-blocks (same-A-panel group), y = m-blocks
    dim3 g1024(1024 / BN, R / BM);
    dim3 g512 ( 512 / BN, R / BM);

    // p1: M1 = ctx @ w_ih^T -> S0
    gemm32g_kernel<false, false><<<g1024, gblk, 0, stream>>>(
        ctx_c, w_ih, nullptr, nullptr, nullptr, S0, 1024, 1024, 1024, 1024, FM1024);
    // p2: out = tanh(((M1 + b_ih) + h0 @ w_hh^T) + b_hh) -> out_h
    gemm32g_kernel<true, true><<<g1024, gblk, 0, stream>>>(
        hid_c, w_hh, b_ih, b_hh, S0, out_c, 1024, 1024, 1024, 1024, FM1024);
    // t1 = tanh(out @ w_cx11^T + b) -> S1
    gemm32g_kernel<true, false><<<g1024, gblk, 0, stream>>>(
        out_c, w_cx11, b_cx11, nullptr, nullptr, S1, 1024, 1024, 1024, 1024, FM1024);
    // cx1 logits = t1 @ w_cx12^T + b -> S0
    gemm32g_kernel<false, false><<<g1024, gblk, 0, stream>>>(
        S1, w_cx12, b_cx12, nullptr, nullptr, S0, 1024, 1024, 1024, 1024, FM1024);
    // x1 = out @ w_l1^T + b -> OX (ctx dead)
    gemm32g_kernel<false, false><<<g1024, gblk, 0, stream>>>(
        out_c, w_l1, b_l1, nullptr, nullptr, OX, 1024, 1024, 1024, 1024, FM1024);
    // x1k = kwta(x1, softmax(cx1)) -> OX
    kwta_kernel<1024><<<R, blk, 0, stream>>>(OX, S0, OX);
    // t2 = tanh(out @ w_cx21^T + b) -> S1.lo
    gemm32g_kernel<true, false><<<g512, gblk, 0, stream>>>(
        out_c, w_cx21, b_cx21, nullptr, nullptr, S1, 512, 1024, 1024, 1024, FM1024);
    // cx2 logits = t2 @ w_cx22^T + b -> S1.hi
    gemm32g_kernel<false, false><<<g512, gblk, 0, stream>>>(
        S1, w_cx22, b_cx22, nullptr, nullptr, S1hi, 512, 512, 512, 512, FM512);
    // x2 = x1k @ w_l2^T + b -> S0.lo (cx1 dead)
    gemm32g_kernel<false, false><<<g512, gblk, 0, stream>>>(
        OX, w_l2, b_l2, nullptr, nullptr, S0, 512, 1024, 1024, 1024, FM1024);
    // x2k = kwta(x2, softmax(cx2)) -> S0.lo
    kwta_kernel<512><<<R, blk, 0, stream>>>(S0, S1hi, S0);
    // t3 = tanh(out @ w_cx31^T + b) -> S1 (t2/cx2 dead)
    gemm32g_kernel<true, false><<<g1024, gblk, 0, stream>>>(
        out_c, w_cx31, b_cx31, nullptr, nullptr, S1, 1024, 1024, 1024, 1024, FM1024);
    // cx3 logits = t3 @ w_cx32^T + b -> OX (x1k dead)
    gemm32g_kernel<false, false><<<g1024, gblk, 0, stream>>>(
        S1, w_cx32, b_cx32, nullptr, nullptr, OX, 1024, 1024, 1024, 1024, FM1024);
    // x3 = x2k @ w_l3^T + b -> S1 (t3 dead)
    gemm32g_kernel<false, false><<<g1024, gblk, 0, stream>>>(
        S0, w_l3, b_l3, nullptr, nullptr, S1, 1024, 512, 512, 512, FM512);
    // x3k = kwta(x3, softmax(cx3)) -> S1
    kwta_kernel<1024><<<R, blk, 0, stream>>>(S1, OX, S1);
    // x4 = x3k @ w_l4^T + b -> OX (final; cx3 dead)
    gemm32g_kernel<false, false><<<g1024, gblk, 0, stream>>>(
        S1, w_l4, b_l4, nullptr, nullptr, OX, 1024, 1024, 1024, 1024, FM1024);
  }
}

// Round 15
// 4262.315 us; speedup vs baseline: 1.0807x; 1.0807x over previous
//
#include <hip/hip_runtime.h>
#include <math.h>

#define BB 16384
#define BM 128
#define BN 128
#define BK 32

typedef float f32x2 __attribute__((ext_vector_type(2)));

// zero-mov packed FMA: cur.{lo,hi} += a_sel * w.{lo,hi}, where a_sel is the
// LO (PKFMA_LO) or HI (PKFMA_HI) dword of the register pair `ap`.
// Pure VOP3P register op, per-component IEEE fp32 rounding == fmaf.
#define PKFMA_LO(c, ap, w) \
  asm("v_pk_fma_f32 %0, %1, %2, %0 op_sel:[0,0,0] op_sel_hi:[0,1,1]" \
      : "+v"(c) : "v"(ap), "v"(w))
#define PKFMA_HI(c, ap, w) \
  asm("v_pk_fma_f32 %0, %1, %2, %0 op_sel:[1,0,0] op_sel_hi:[1,1,1]" \
      : "+v"(c) : "v"(ap), "v"(w))

// ---------------------------------------------------------------------------
// ctx = concat(input[B,510], task[B,514]) -> [B,1024] fp32 (exact)
// ---------------------------------------------------------------------------
__global__ __launch_bounds__(256) void concat_kernel(const float* __restrict__ inp,
    const float* __restrict__ task, float* __restrict__ ctx)
{
  int idx = blockIdx.x * 256 + threadIdx.x;
  int b = idx >> 10;
  int c = idx & 1023;
  float v;
  if (c < 510) v = inp[(size_t)b * 510 + c];
  else         v = task[(size_t)b * 514 + (c - 510)];
  ctx[idx] = v;
}

// ---------------------------------------------------------------------------
// Bitwise-BLAS fp32 GEMM, K-chunking = FIXED 384-blocks, remainder last:
// K=1024 -> [384,384,256] (fold after BK-tiles 11,23,31), K=512 -> [384,128]
// (fold after 11,15). Per kc-block: single ascending-k fp32 FMA chain per C
// element; blocks folded left-assoc (C += partial). Verified np match (r7)
// -- DO NOT REORDER chains or fold points.
// r15 change: inner loop = inline-asm v_pk_fma_f32 with op_sel broadcast of
// the A scalar straight out of the ds_read_b128 quad (no pair-building movs
// -- r13/r14 diag: ~100-150us/dispatch of non-FMA VALU). Same fp32 FMAs in
// the same order -> bit-identical. r13 structure otherwise: 128x128x32,
// 256 thr, 8x8 micro, LDS dbuf single barrier, XOR swizzle [k][r^(k&28)]
// (0 conflicts), bijective XCD chunk swizzle, (256,2) VGPR budget.
// post (CIN=0): acc + b1 ; post (CIN=1): ((Cin + b1) + acc) + b2 (np order)
// tanh: correctly-rounded via double.
// ---------------------------------------------------------------------------
template<bool TANH, bool CIN>
__global__ __launch_bounds__(256, 2) void gemm32g_kernel(
    const float* __restrict__ A, const float* __restrict__ W,
    const float* __restrict__ b1, const float* __restrict__ b2,
    const float* __restrict__ Cin, float* __restrict__ C,
    int N, int K, int lda, int ldw, unsigned foldmask)
{
  __shared__ float As[2][BK * BM];
  __shared__ float Bs[2][BK * BN];
  const int tid = threadIdx.x;
  const int tx = tid & 15;            // 8 cols: 4*tx and 64+4*tx
  const int ty = tid >> 4;            // 8 rows: 4*ty and 64+4*ty
  // XCD-chunked bijective block swizzle (nwg multiple of 8 by construction)
  const int gx = gridDim.x;
  const int nwg = gx * gridDim.y;
  const int flat = blockIdx.y * gx + blockIdx.x;
  const int cpx = nwg >> 3;
  const int swb = (flat & 7) * cpx + (flat >> 3);
  const int m0 = (swb / gx) * BM;
  const int n0 = (swb % gx) * BN;
  const int rrow = tid >> 3;          // 0..31
  const int kc = (tid & 7) << 2;      // 0,4,...,28

  // accumulators: [g][h][i][jp]; i = row-in-quad (0..3), jp = col pair
  f32x2 res[2][2][4][2], cur[2][2][4][2];
#pragma unroll
  for (int g = 0; g < 2; ++g)
#pragma unroll
    for (int h = 0; h < 2; ++h)
#pragma unroll
      for (int i = 0; i < 4; ++i)
#pragma unroll
        for (int jp = 0; jp < 2; ++jp) {
          res[g][h][i][jp] = (f32x2){0.f, 0.f};
          cur[g][h][i][jp] = (f32x2){0.f, 0.f};
        }

  float4 ra[4], rb[4];
  const int NT = K / BK;

  auto loadG = [&](int kt) {
    int kb = kt * BK;
#pragma unroll
    for (int i = 0; i < 4; ++i) {
      int r = rrow + (i << 5);
      ra[i] = *(const float4*)(A + (size_t)(m0 + r) * lda + kb + kc);
      rb[i] = *(const float4*)(W + (size_t)(n0 + r) * ldw + kb + kc);
    }
  };
  auto stage = [&](int p) {
#pragma unroll
    for (int i = 0; i < 4; ++i) {
      int cS = (rrow + (i << 5)) ^ kc;      // swizzled staging (r7/r9-verified)
      As[p][(kc + 0) * BM + cS] = ra[i].x;
      As[p][(kc + 1) * BM + cS] = ra[i].y;
      As[p][(kc + 2) * BM + cS] = ra[i].z;
      As[p][(kc + 3) * BM + cS] = ra[i].w;
      Bs[p][(kc + 0) * BN + cS] = rb[i].x;
      Bs[p][(kc + 1) * BN + cS] = rb[i].y;
      Bs[p][(kc + 2) * BN + cS] = rb[i].z;
      Bs[p][(kc + 3) * BN + cS] = rb[i].w;
    }
  };

  // prologue: stage kt=0 into buf0; start loads for kt=1
  loadG(0);
  stage(0);
  __syncthreads();
  if (NT > 1) loadG(1);

  for (int kt = 0; kt < NT; ++kt) {
    const int p = kt & 1;
    if (kt + 1 < NT) {
      stage(p ^ 1);
      if (kt + 2 < NT) loadG(kt + 2);
    }
    // compute from buf[p]: fully-unrolled kk, 2-deep fragment pipeline
    {
      const float* Ap = As[p];
      const float* Bp = Bs[p];
      float4 a0f[2], a1f[2], b0f[2], b1f[2];
      a0f[0] = *(const float4*)&Ap[(4 * ty)];
      a1f[0] = *(const float4*)&Ap[64 + (4 * ty)];
      b0f[0] = *(const float4*)&Bp[(4 * tx)];
      b1f[0] = *(const float4*)&Bp[64 + (4 * tx)];
#pragma unroll
      for (int kk = 0; kk < BK; ++kk) {
        const int q = kk & 1;
        if (kk + 1 < BK) {
          const int swz = (kk + 1) & 28;
          a0f[q ^ 1] = *(const float4*)&Ap[(kk + 1) * BM + ((4 * ty) ^ swz)];
          a1f[q ^ 1] = *(const float4*)&Ap[(kk + 1) * BM + 64 + ((4 * ty) ^ swz)];
          b0f[q ^ 1] = *(const float4*)&Bp[(kk + 1) * BN + ((4 * tx) ^ swz)];
          b1f[q ^ 1] = *(const float4*)&Bp[(kk + 1) * BN + 64 + ((4 * tx) ^ swz)];
        }
        // A scalars live in the loaded quads: (x,y) = lo pair, (z,w) = hi pair
        const f32x2 aP[2][2] = {
          {*(const f32x2*)&a0f[q].x, *(const f32x2*)&a0f[q].z},
          {*(const f32x2*)&a1f[q].x, *(const f32x2*)&a1f[q].z}};
        const f32x2 wP[2][2] = {
          {*(const f32x2*)&b0f[q].x, *(const f32x2*)&b0f[q].z},
          {*(const f32x2*)&b1f[q].x, *(const f32x2*)&b1f[q].z}};
#pragma unroll
        for (int g = 0; g < 2; ++g)
#pragma unroll
          for (int h = 0; h < 2; ++h)
#pragma unroll
            for (int jp = 0; jp < 2; ++jp) {
              PKFMA_LO(cur[g][h][0][jp], aP[g][0], wP[h][jp]);  // a = quad.x
              PKFMA_HI(cur[g][h][1][jp], aP[g][0], wP[h][jp]);  // a = quad.y
              PKFMA_LO(cur[g][h][2][jp], aP[g][1], wP[h][jp]);  // a = quad.z
              PKFMA_HI(cur[g][h][3][jp], aP[g][1], wP[h][jp]);  // a = quad.w
            }
      }
    }
    if ((foldmask >> kt) & 1u) {        // kc-block boundary: C += partial
#pragma unroll
      for (int g = 0; g < 2; ++g)
#pragma unroll
        for (int h = 0; h < 2; ++h)
#pragma unroll
          for (int i = 0; i < 4; ++i)
#pragma unroll
            for (int jp = 0; jp < 2; ++jp) {
              res[g][h][i][jp] = res[g][h][i][jp] + cur[g][h][i][jp];  // v_pk_add_f32
              cur[g][h][i][jp] = (f32x2){0.f, 0.f};
            }
    }
    __syncthreads();                    // single barrier per kt
  }

  // epilogue with np-exact rounding order
  float4 b1v[2], b2v[2];
#pragma unroll
  for (int h = 0; h < 2; ++h) {
    int cb = n0 + h * 64 + 4 * tx;
    b1v[h] = b1 ? *(const float4*)&b1[cb] : make_float4(0.f, 0.f, 0.f, 0.f);
    b2v[h] = (CIN && b2) ? *(const float4*)&b2[cb] : make_float4(0.f, 0.f, 0.f, 0.f);
  }
#pragma unroll
  for (int g = 0; g < 2; ++g)
#pragma unroll
    for (int i = 0; i < 4; ++i) {
      int row = m0 + g * 64 + 4 * ty + i;
#pragma unroll
      for (int h = 0; h < 2; ++h) {
        int col = n0 + h * 64 + 4 * tx;
        const float rs[4] = {res[g][h][i][0][0], res[g][h][i][0][1],
                             res[g][h][i][1][0], res[g][h][i][1][1]};
        float4 o;
        if (CIN) {
          float4 ci = *(const float4*)&Cin[(size_t)row * N + col];
          o.x = ((ci.x + b1v[h].x) + rs[0]) + b2v[h].x;
          o.y = ((ci.y + b1v[h].y) + rs[1]) + b2v[h].y;
          o.z = ((ci.z + b1v[h].z) + rs[2]) + b2v[h].z;
          o.w = ((ci.w + b1v[h].w) + rs[3]) + b2v[h].w;
        } else if (b1) {
          o.x = rs[0] + b1v[h].x;
          o.y = rs[1] + b1v[h].y;
          o.z = rs[2] + b1v[h].z;
          o.w = rs[3] + b1v[h].w;
        } else {
          o.x = rs[0]; o.y = rs[1]; o.z = rs[2]; o.w = rs[3];
        }
        if (TANH) {
          o.x = (float)tanh((double)o.x);
          o.y = (float)tanh((double)o.y);
          o.z = (float)tanh((double)o.z);
          o.w = (float)tanh((double)o.w);
        }
        *(float4*)&C[(size_t)row * N + col] = o;
      }
    }
}

// ---------------------------------------------------------------------------
// kwta replicating np-fp32 (verified round 7): cxz = softmax LOGITS row.
//   m = max(z); e = expCR(z-m); s = numpy-pairwise-sum(e); u = e/s
//   k = first-argmax(u); thr = ascending-rank-(N-k) of x (exact radix select)
//   out = (k>0 && x>=thr) ? x : x/3.0f   (in-place safe)
// ---------------------------------------------------------------------------
template<int NELEM>
__global__ __launch_bounds__(256) void kwta_kernel(const float* __restrict__ x,
    const float* __restrict__ cxz, float* __restrict__ out)
{
  constexpr int NPER = NELEM / 256;
  const int row = blockIdx.x;
  const int tid = threadIdx.x;
  const float* xr = x + (size_t)row * NELEM;
  const float* zr = cxz + (size_t)row * NELEM;
  float* orow = out + (size_t)row * NELEM;

  __shared__ float es[NELEM];
  __shared__ float red[256];
  __shared__ int   ri[256];
  __shared__ float bs[8];
  __shared__ float ssum;
  __shared__ unsigned hist[256];
  __shared__ unsigned cum[256];
  __shared__ int selBin;
  __shared__ unsigned selBase;

  float zv[NPER];
  float mx = -INFINITY;
#pragma unroll
  for (int j = 0; j < NPER; ++j) {
    zv[j] = zr[tid + (j << 8)];
    mx = fmaxf(mx, zv[j]);
  }
  red[tid] = mx;
  __syncthreads();
  for (int s = 128; s > 0; s >>= 1) {
    if (tid < s) red[tid] = fmaxf(red[tid], red[tid + s]);
    __syncthreads();
  }
  mx = red[0];
  __syncthreads();

  float ev[NPER];
#pragma unroll
  for (int j = 0; j < NPER; ++j) {
    float d = zv[j] - mx;
    ev[j] = (float)exp((double)d);              // correctly-rounded expf
    es[tid + (j << 8)] = ev[j];
  }
  __syncthreads();

  if (tid < NELEM / 128) {                      // numpy pairwise 128-blocks
    const float* a = &es[tid * 128];
    float r0 = a[0], r1 = a[1], r2 = a[2], r3 = a[3];
    float r4 = a[4], r5 = a[5], r6 = a[6], r7 = a[7];
    for (int i = 8; i < 128; i += 8) {
      r0 += a[i + 0]; r1 += a[i + 1]; r2 += a[i + 2]; r3 += a[i + 3];
      r4 += a[i + 4]; r5 += a[i + 5]; r6 += a[i + 6]; r7 += a[i + 7];
    }
    bs[tid] = ((r0 + r1) + (r2 + r3)) + ((r4 + r5) + (r6 + r7));
  }
  __syncthreads();
  if (tid == 0) {
    float s;
    if (NELEM == 1024)
      s = ((bs[0] + bs[1]) + (bs[2] + bs[3])) + ((bs[4] + bs[5]) + (bs[6] + bs[7]));
    else
      s = (bs[0] + bs[1]) + (bs[2] + bs[3]);
    ssum = s;
  }
  __syncthreads();
  const float s = ssum;

  float bv = -INFINITY; int bi = 0x7fffffff;
#pragma unroll
  for (int j = 0; j < NPER; ++j) {
    float u = ev[j] / s;
    int i = tid + (j << 8);
    if (u > bv) { bv = u; bi = i; }
  }
  red[tid] = bv; ri[tid] = bi;
  __syncthreads();
  for (int st = 128; st > 0; st >>= 1) {
    if (tid < st) {
      float ov = red[tid + st]; int oi = ri[tid + st];
      if (ov > red[tid] || (ov == red[tid] && oi < ri[tid])) { red[tid] = ov; ri[tid] = oi; }
    }
    __syncthreads();
  }
  const int k = ri[0];

  float xv[NPER]; unsigned key[NPER];
#pragma unroll
  for (int j = 0; j < NPER; ++j) {
    float v = xr[tid + (j << 8)];
    xv[j] = v;
    unsigned sb = __float_as_uint(v);
    key[j] = (sb & 0x80000000u) ? ~sb : (sb | 0x80000000u);
  }

  float thr = 0.f;
  const bool kzero = (k == 0);
  if (!kzero) {
    unsigned ur = (unsigned)(NELEM - k);        // ascending 0-indexed rank
    unsigned prefix = 0, pmask = 0;
    for (int shift = 24; shift >= 0; shift -= 8) {
      hist[tid] = 0;
      __syncthreads();
#pragma unroll
      for (int j = 0; j < NPER; ++j)
        if ((key[j] & pmask) == prefix) atomicAdd(&hist[(key[j] >> shift) & 255u], 1u);
      __syncthreads();
      unsigned v = hist[tid];
      cum[tid] = v;
      __syncthreads();
      for (int d = 1; d < 256; d <<= 1) {
        unsigned t = (tid >= d) ? cum[tid - d] : 0u;
        __syncthreads();
        v += t; cum[tid] = v;
        __syncthreads();
      }
      unsigned excl = v - hist[tid];
      if (ur >= excl && ur < v) { selBin = tid; selBase = excl; }
      __syncthreads();
      prefix |= ((unsigned)selBin) << shift;
      pmask  |= (255u << shift);
      ur -= selBase;
      __syncthreads();
    }
    thr = (prefix & 0x80000000u) ? __uint_as_float(prefix & 0x7FFFFFFFu)
                                 : __uint_as_float(~prefix);
  }
#pragma unroll
  for (int j = 0; j < NPER; ++j) {
    float v = xv[j];
    bool keep = !kzero && (v >= thr);
    orow[tid + (j << 8)] = keep ? v : (v / 3.0f);
  }
}

// ---------------------------------------------------------------------------
// Schedule: fp32, 2 ws slots (R*1024 fp32 each), row-chunked (fits ws_size).
//   concat -> out_x.  Per chunk:
//   p1 M1=ctx@w_ihT -> S0;  p2 out=tanh(((M1+b_ih)+h0@w_hhT)+b_hh) -> out_h
//   t1->S1; cx1->S0; x1->OX; kw1(OX,S0)->OX;
//   t2->S1.lo; cx2->S1.hi; x2->S0.lo; kw2(S0.lo,S1.hi)->S0.lo;
//   t3->S1; cx3->OX; x3->S1; kw3(S1,OX)->S1; x4->OX (final).
// ---------------------------------------------------------------------------
extern "C" void kernel_launch(void* const* d_in, const int* in_sizes, int n_in,
                              void* d_out, int out_size, void* d_ws, size_t ws_size,
                              hipStream_t stream) {
  const float* input  = (const float*)d_in[0];
  const float* task   = (const float*)d_in[1];
  const float* hidden = (const float*)d_in[2];
  const float* w_ih   = (const float*)d_in[3];  const float* b_ih   = (const float*)d_in[4];
  const float* w_hh   = (const float*)d_in[5];  const float* b_hh   = (const float*)d_in[6];
  const float* w_cx11 = (const float*)d_in[7];  const float* b_cx11 = (const float*)d_in[8];
  const float* w_cx12 = (const float*)d_in[9];  const float* b_cx12 = (const float*)d_in[10];
  const float* w_cx21 = (const float*)d_in[11]; const float* b_cx21 = (const float*)d_in[12];
  const float* w_cx22 = (const float*)d_in[13]; const float* b_cx22 = (const float*)d_in[14];
  const float* w_cx31 = (const float*)d_in[15]; const float* b_cx31 = (const float*)d_in[16];
  const float* w_cx32 = (const float*)d_in[17]; const float* b_cx32 = (const float*)d_in[18];
  const float* w_l1   = (const float*)d_in[19]; const float* b_l1   = (const float*)d_in[20];
  const float* w_l2   = (const float*)d_in[21]; const float* b_l2   = (const float*)d_in[22];
  const float* w_l3   = (const float*)d_in[23]; const float* b_l3   = (const float*)d_in[24];
  const float* w_l4   = (const float*)d_in[25]; const float* b_l4   = (const float*)d_in[26];

  float* out_x = (float*)d_out;                 // x [B,1024]; ctx scratch until final
  float* out_h = out_x + (size_t)BB * 1024;     // next_hidden [B,1024]

  int R = BB;                                   // 2 slots * R*4096 B <= ws_size
  while ((size_t)R * 8192 > ws_size && R > 128) R >>= 1;
  const int nChunks = BB / R;

  // Fixed-384 K-chunking (verified round 7): K=1024 -> [384,384,256]
  // (folds after BK-tiles 11,23,31); K=512 -> [384,128] (folds after 11,15).
  const unsigned FM1024 = (1u << 11) | (1u << 23) | (1u << 31);
  const unsigned FM512  = (1u << 11) | (1u << 15);

  dim3 blk(256);

  concat_kernel<<<BB * 1024 / 256, blk, 0, stream>>>(input, task, out_x);

  for (int c = 0; c < nChunks; ++c) {
    const size_t r0 = (size_t)c * R;
    float* S0 = (float*)d_ws;
    float* S1 = S0 + (size_t)R * 1024;
    float* S1hi = S1 + (size_t)R * 512;
    float* OX = out_x + r0 * 1024;
    const float* ctx_c = OX;
    const float* hid_c = hidden + r0 * 1024;
    float* out_c = out_h + r0 * 1024;
    // grid: x = n-blocks (same-A-panel group), y = m-blocks
    dim3 g1024(1024 / BN, R / BM);
    dim3 g512 ( 512 / BN, R / BM);

    // p1: M1 = ctx @ w_ih^T -> S0
    gemm32g_kernel<false, false><<<g1024, blk, 0, stream>>>(
        ctx_c, w_ih, nullptr, nullptr, nullptr, S0, 1024, 1024, 1024, 1024, FM1024);
    // p2: out = tanh(((M1 + b_ih) + h0 @ w_hh^T) + b_hh) -> out_h
    gemm32g_kernel<true, true><<<g1024, blk, 0, stream>>>(
        hid_c, w_hh, b_ih, b_hh, S0, out_c, 1024, 1024, 1024, 1024, FM1024);
    // t1 = tanh(out @ w_cx11^T + b) -> S1
    gemm32g_kernel<true, false><<<g1024, blk, 0, stream>>>(
        out_c, w_cx11, b_cx11, nullptr, nullptr, S1, 1024, 1024, 1024, 1024, FM1024);
    // cx1 logits = t1 @ w_cx12^T + b -> S0
    gemm32g_kernel<false, false><<<g1024, blk, 0, stream>>>(
        S1, w_cx12, b_cx12, nullptr, nullptr, S0, 1024, 1024, 1024, 1024, FM1024);
    // x1 = out @ w_l1^T + b -> OX (ctx dead)
    gemm32g_kernel<false, false><<<g1024, blk, 0, stream>>>(
        out_c, w_l1, b_l1, nullptr, nullptr, OX, 1024, 1024, 1024, 1024, FM1024);
    // x1k = kwta(x1, softmax(cx1)) -> OX
    kwta_kernel<1024><<<R, blk, 0, stream>>>(OX, S0, OX);
    // t2 = tanh(out @ w_cx21^T + b) -> S1.lo
    gemm32g_kernel<true, false><<<g512, blk, 0, stream>>>(
        out_c, w_cx21, b_cx21, nullptr, nullptr, S1, 512, 1024, 1024, 1024, FM1024);
    // cx2 logits = t2 @ w_cx22^T + b -> S1.hi
    gemm32g_kernel<false, false><<<g512, blk, 0, stream>>>(
        S1, w_cx22, b_cx22, nullptr, nullptr, S1hi, 512, 512, 512, 512, FM512);
    // x2 = x1k @ w_l2^T + b -> S0.lo (cx1 dead)
    gemm32g_kernel<false, false><<<g512, blk, 0, stream>>>(
        OX, w_l2, b_l2, nullptr, nullptr, S0, 512, 1024, 1024, 1024, FM1024);
    // x2k = kwta(x2, softmax(cx2)) -> S0.lo
    kwta_kernel<512><<<R, blk, 0, stream>>>(S0, S1hi, S0);
    // t3 = tanh(out @ w_cx31^T + b) -> S1 (t2/cx2 dead)
    gemm32g_kernel<true, false><<<g1024, blk, 0, stream>>>(
        out_c, w_cx31, b_cx31, nullptr, nullptr, S1, 1024, 1024, 1024, 1024, FM1024);
    // cx3 logits = t3 @ w_cx32^T + b -> OX (x1k dead)
    gemm32g_kernel<false, false><<<g1024, blk, 0, stream>>>(
        S1, w_cx32, b_cx32, nullptr, nullptr, OX, 1024, 1024, 1024, 1024, FM1024);
    // x3 = x2k @ w_l3^T + b -> S1 (t3 dead)
    gemm32g_kernel<false, false><<<g1024, blk, 0, stream>>>(
        S0, w_l3, b_l3, nullptr, nullptr, S1, 1024, 512, 512, 512, FM512);
    // x3k = kwta(x3, softmax(cx3)) -> S1
    kwta_kernel<1024><<<R, blk, 0, stream>>>(S1, OX, S1);
    // x4 = x3k @ w_l4^T + b -> OX (final; cx3 dead)
    gemm32g_kernel<false, false><<<g1024, blk, 0, stream>>>(
        S1, w_l4, b_l4, nullptr, nullptr, OX, 1024, 1024, 1024, 1024, FM1024);
  }
}